// Round 12
// baseline (240.996 us; speedup 1.0000x reference)
//
#include <hip/hip_runtime.h>
#include <hip/hip_bf16.h>
#include <stdint.h>

#define DI __device__ __forceinline__

typedef float f32x4 __attribute__((ext_vector_type(4)));
typedef short bf16x8 __attribute__((ext_vector_type(8)));

constexpr int BATCH = 4;
constexpr int C = 256;       // channels (= d_v)
constexpr int N = 4096;      // H*W
constexpr int NO = 320;      // 32 q + 32 k + 256 v output rows
constexpr int KB2 = 64;      // keys per attention iteration
constexpr int NT2 = N / KB2; // 64 iterations
constexpr float LOG2E = 1.44269504088896340736f;

DI unsigned short f2bf(float f) {
  union { float f; unsigned int i; } v; v.f = f;
  unsigned int r = v.i + 0x7fffu + ((v.i >> 16) & 1u);   // RNE
  return (unsigned short)(r >> 16);
}

DI float exp2i(float x) {  // raw v_exp_f32 (D = 2^S0)
  float r; asm("v_exp_f32 %0, %1" : "=v"(r) : "v"(x)); return r;
}

// ---------------- kernel 0: pack weights/biases to bf16 ----------------
// Wq/bq pre-scaled by log2e so attention scores come out in log2 domain.
__global__ __launch_bounds__(256) void prep_kernel(
    const float* __restrict__ Wq, const float* __restrict__ Wk, const float* __restrict__ Wv,
    const float* __restrict__ bq, const float* __restrict__ bk, const float* __restrict__ bv,
    unsigned short* __restrict__ Wcat, float* __restrict__ bcat) {
  int idx = blockIdx.x * 256 + threadIdx.x;
  if (idx < NO * C) {
    int row = idx >> 8, c = idx & 255;
    float v = (row < 32) ? Wq[row * 256 + c] * LOG2E
            : (row < 64) ? Wk[(row - 32) * 256 + c]
                         : Wv[(row - 64) * 256 + c];
    Wcat[idx] = f2bf(v);
  }
  if (idx < NO) {
    float v = (idx < 32) ? bq[idx] * LOG2E
            : (idx < 64) ? bk[idx - 32] : bv[idx - 64];
    bcat[idx] = v;
  }
}

// ---------------- kernel 1: QKV projection (MFMA, deep z-split) ----------------
// out[n,o] = sum_c x[c,n] * Wcat[o,c] + bcat[o]
// z-block handles 2 of 20 o-tiles: z=0 -> q ; z=1 -> k ; z=2..9 -> 32 v-rows each.
__global__ __launch_bounds__(256) void proj_kernel(
    const float* __restrict__ x, const unsigned short* __restrict__ Wcat,
    const float* __restrict__ bcat,
    unsigned short* __restrict__ qarr, unsigned short* __restrict__ karr,
    unsigned short* __restrict__ vT) {
  // stride 66 u16: gather row-step 8 words -> spreads all 32 banks (2-way, free)
  __shared__ __align__(16) unsigned short ldsx[C][66];  // 33.8KB

  int b = blockIdx.y, n0 = blockIdx.x * 64, z = blockIdx.z;
  int t = threadIdx.x, lane = t & 63, w = t >> 6;
  int g = lane >> 4, cq = lane & 15;

  // stage x tile [256c][64n] -> bf16 LDS (float4 loads)
  const float* xb = x + (size_t)b * C * N;
  {
    int csub = lane >> 4, m = lane & 15;
    #pragma unroll 4
    for (int cc = 0; cc < 16; ++cc) {
      int c = cc * 16 + w * 4 + csub;
      f32x4 v = *(const f32x4*)(xb + (size_t)c * N + n0 + m * 4);
      unsigned int p01 = ((unsigned int)f2bf(v[0])) | ((unsigned int)f2bf(v[1]) << 16);
      unsigned int p23 = ((unsigned int)f2bf(v[2])) | ((unsigned int)f2bf(v[3]) << 16);
      *(unsigned int*)(&ldsx[c][m * 4]) = p01;
      *(unsigned int*)(&ldsx[c][m * 4 + 2]) = p23;
    }
  }
  __syncthreads();

  // gather A-frags: A[row=n][k=c], lane holds row=w*16+cq, k=(g*8..+7) per 32-k step
  bf16x8 afrag[8];
  int nrow = w * 16 + cq;
  #pragma unroll
  for (int ks = 0; ks < 8; ++ks) {
    bf16x8 a;
    #pragma unroll
    for (int j = 0; j < 8; ++j) a[j] = (short)ldsx[ks * 32 + g * 8 + j][nrow];
    afrag[ks] = a;
  }
  __syncthreads();  // done reading ldsx; reuse as v-transpose buffer

  unsigned short (*vlds)[66] = (unsigned short (*)[66]) & ldsx[0][0];  // [64n][66]

  #pragma unroll
  for (int i = 0; i < 2; ++i) {
    int oc = z * 2 + i;
    int o = oc * 16 + cq;
    f32x4 acc = {0.f, 0.f, 0.f, 0.f};
    const unsigned short* wrow = Wcat + o * 256;  // B[k=c][col=o], 16B contig
    #pragma unroll
    for (int ks = 0; ks < 8; ++ks) {
      bf16x8 bf = *(const bf16x8*)(wrow + ks * 32 + g * 8);
      acc = __builtin_amdgcn_mfma_f32_16x16x32_bf16(afrag[ks], bf, acc, 0, 0, 0);
    }
    float bias = bcat[o];
    // D: row(local n) = g*4+r, col = o
    if (z < 2) {
      unsigned short* dst = (z == 0) ? qarr : karr;
      int od = ((oc & 1) << 4) + cq;
      #pragma unroll
      for (int r = 0; r < 4; ++r) {
        int n = n0 + w * 16 + g * 4 + r;
        dst[((size_t)b * N + n) * 32 + od] = f2bf(acc[r] + bias);
      }
    } else {
      int el = i * 16 + cq;  // e-local 0..31
      #pragma unroll
      for (int r = 0; r < 4; ++r)
        vlds[w * 16 + g * 4 + r][el] = f2bf(acc[r] + bias);
    }
  }

  if (z >= 2) {
    __syncthreads();
    int e0 = (z - 2) * 32;
    // coalesced vT write: lane = n column, wave strides over e-local rows
    #pragma unroll 4
    for (int ep = 0; ep < 8; ++ep) {
      int el = ep * 4 + w;
      vT[((size_t)b * 256 + e0 + el) * N + n0 + lane] = vlds[lane][el];
    }
  }
}

// ---------------- kernel 2: attention (512 blocks, 32-q tiles, statless) ----------------
// Block = (batch, 32-q tile). 8 waves, 512 thr, 2 blocks/CU -> 4 waves/SIMD.
// Score: wave w -> q-subtile (w&1)*16, key-quarter (w>>1)*16 of KB=64 (no duplication).
// PV: wave w owns e in [w*32, w*32+32) x all 32 q.
// p = 2^(s' - 20*log2e) (Q pre-scaled); L by per-lane accumulation + end reduce.
__global__ __launch_bounds__(512, 4) void attn_kernel(
    const unsigned short* __restrict__ qarr, const unsigned short* __restrict__ karr,
    const unsigned short* __restrict__ vT, const float* __restrict__ x,
    const float* __restrict__ gamma_p, float* __restrict__ out) {
  // P: [buf][32 q][64 k + pad] u16, row stride 136 u16 = 272B (16B-aligned rows).
  // b16 writes ~4-way (4 instrs, minor); b128 reads at the inherent 8-phase floor.
  __shared__ __align__(16) unsigned short plds[2][32][136];  // 17.4 KB
  __shared__ float lred[4][32];
  __shared__ float lsc[32];

  int bid = blockIdx.x;
  // bijective XCD swizzle: batch b resident on XCDs {2b,2b+1}; K/Q/V ~2.5MB < 4MB L2
  int xcd = bid & 7;
  int b = xcd >> 1;
  int tile = ((bid >> 3) << 1) | (bid & 1);  // 0..127

  int t = threadIdx.x, lane = t & 63, w = t >> 6;
  int g = lane >> 4, cq = lane & 15;
  int qw = w & 1, kh = w >> 1;  // score roles: 2 q-subtiles x 4 key-quarters

  const unsigned short* kb = karr + (size_t)b * N * 32;
  const unsigned short* vTb = vT + (size_t)b * C * N;

  // Q A-frag: A[row=q=cq][k=d=g*8..+7]
  bf16x8 qf = *(const bf16x8*)(qarr + ((size_t)b * N + tile * 32 + qw * 16 + cq) * 32 + g * 8);

  f32x4 o[2][2];   // [ec][qc]: e = w*32 + ec*16 + (g*4+r), q(col) = qc*16 + cq
  #pragma unroll
  for (int i = 0; i < 2; ++i)
    #pragma unroll
    for (int j = 0; j < 2; ++j) o[i][j] = f32x4{0.f, 0.f, 0.f, 0.f};
  float Ls[4] = {0.f, 0.f, 0.f, 0.f};  // per-lane partial row-sums

  // V A-frag: e = w*32 + ec*16 + cq, k-chunk g*8 (+kc*32 +nn)
  const unsigned short* vbase = vTb + (size_t)(w * 32 + cq) * N + g * 8;
  // K B-frag: key = kh*16 + cq (+nn), d-chunk g*8
  const unsigned short* kbase = kb + (size_t)(kh * 16 + cq) * 32 + g * 8;

  // prologue: iter-0 operands
  bf16x8 kf = *(const bf16x8*)(kbase);
  bf16x8 vf[2][2];
  #pragma unroll
  for (int ec = 0; ec < 2; ++ec)
    #pragma unroll
    for (int kc = 0; kc < 2; ++kc)
      vf[ec][kc] = *(const bf16x8*)(vbase + (size_t)ec * 16 * N + kc * 32);

  const float C2 = 20.0f * LOG2E;  // shift in log2 domain

  for (int nt = 0; nt < NT2; ++nt) {
    int pb = nt & 1;
    int nn2 = ((nt + 1) & (NT2 - 1)) * KB2;  // next tile, wrapped

    // prefetch next-iter K and V (full iteration of latency to land)
    bf16x8 nk = *(const bf16x8*)(kbase + (size_t)nn2 * 32);
    bf16x8 nv[2][2];
    #pragma unroll
    for (int ec = 0; ec < 2; ++ec)
      #pragma unroll
      for (int kc = 0; kc < 2; ++kc)
        nv[ec][kc] = *(const bf16x8*)(vbase + (size_t)ec * 16 * N + nn2 + kc * 32);

    // scores (log2 domain): D[row=q=g*4+r][col=key=kh*16+cq]
    f32x4 s = __builtin_amdgcn_mfma_f32_16x16x32_bf16(qf, kf, f32x4{0.f,0.f,0.f,0.f}, 0, 0, 0);

    // p = 2^(s - C2); per-lane L accumulation (free); b16 stores to P tile
    #pragma unroll
    for (int r = 0; r < 4; ++r) {
      float p = exp2i(s[r] - C2);
      Ls[r] += p;
      plds[pb][qw * 16 + g * 4 + r][kh * 16 + cq] = f2bf(p);
    }

    // make P visible WITHOUT draining vmcnt (K/V prefetch stays in flight)
    asm volatile("s_waitcnt lgkmcnt(0)\n\ts_barrier" ::: "memory");

    // PV: O^T[e][q] += V^T[e][n] * P^T[n][q]
    __builtin_amdgcn_s_setprio(1);
    #pragma unroll
    for (int qc = 0; qc < 2; ++qc) {
      const unsigned short* prow = &plds[pb][qc * 16 + cq][0];
      bf16x8 pf0 = *(const bf16x8*)(prow + g * 8);        // keys 0..31
      bf16x8 pf1 = *(const bf16x8*)(prow + 32 + g * 8);   // keys 32..63
      o[0][qc] = __builtin_amdgcn_mfma_f32_16x16x32_bf16(vf[0][0], pf0, o[0][qc], 0, 0, 0);
      o[0][qc] = __builtin_amdgcn_mfma_f32_16x16x32_bf16(vf[0][1], pf1, o[0][qc], 0, 0, 0);
      o[1][qc] = __builtin_amdgcn_mfma_f32_16x16x32_bf16(vf[1][0], pf0, o[1][qc], 0, 0, 0);
      o[1][qc] = __builtin_amdgcn_mfma_f32_16x16x32_bf16(vf[1][1], pf1, o[1][qc], 0, 0, 0);
    }
    __builtin_amdgcn_s_setprio(0);

    kf = nk;
    #pragma unroll
    for (int ec = 0; ec < 2; ++ec)
      #pragma unroll
      for (int kc = 0; kc < 2; ++kc)
        vf[ec][kc] = nv[ec][kc];
  }

  // L: reduce per-lane partials over the 16 key-lanes, then across key-quarters
  #pragma unroll
  for (int r = 0; r < 4; ++r) {
    #pragma unroll
    for (int d = 1; d <= 8; d <<= 1) Ls[r] += __shfl_xor(Ls[r], d);
  }
  if (cq == 0) {
    #pragma unroll
    for (int r = 0; r < 4; ++r) lred[kh][qw * 16 + g * 4 + r] = Ls[r];
  }
  __syncthreads();
  if (t < 32) {
    float L = lred[0][t] + lred[1][t] + lred[2][t] + lred[3][t];
    lsc[t] = gamma_p[0] / L;
  }
  __syncthreads();

  // epilogue: out[b][e][q] = scale[q] * O^T[e][q] + x[b][e][q]
  const float* xb = x + (size_t)b * C * N;
  float* ob = out + (size_t)b * C * N;
  #pragma unroll
  for (int qc = 0; qc < 2; ++qc) {
    float scale = lsc[qc * 16 + cq];
    int qg = tile * 32 + qc * 16 + cq;
    #pragma unroll
    for (int ec = 0; ec < 2; ++ec) {
      #pragma unroll
      for (int r = 0; r < 4; ++r) {
        int e = w * 32 + ec * 16 + g * 4 + r;
        size_t idx = (size_t)e * N + qg;
        ob[idx] = o[ec][qc][r] * scale + xb[idx];
      }
    }
  }
}

// ---------------- launch ----------------
extern "C" void kernel_launch(void* const* d_in, const int* in_sizes, int n_in,
                              void* d_out, int out_size, void* d_ws, size_t ws_size,
                              hipStream_t stream) {
  const float* x  = (const float*)d_in[0];
  const float* Wq = (const float*)d_in[1];
  const float* bq = (const float*)d_in[2];
  const float* Wk = (const float*)d_in[3];
  const float* bk = (const float*)d_in[4];
  const float* Wv = (const float*)d_in[5];
  const float* bv = (const float*)d_in[6];
  const float* gamma = (const float*)d_in[7];
  float* out = (float*)d_out;

  char* ws = (char*)d_ws;
  unsigned short* Wcat = (unsigned short*)(ws);               // 320*256*2 = 163840
  float* bcat          = (float*)(ws + 163840);               // 320*4     = 1280
  unsigned short* qarr = (unsigned short*)(ws + 165120);      // 4*4096*32*2 = 1048576
  unsigned short* karr = (unsigned short*)(ws + 1213696);     // 1048576
  unsigned short* vT   = (unsigned short*)(ws + 2262272);     // 4*256*4096*2 = 8388608
  // total ws use: 10,650,880 bytes

  prep_kernel<<<320, 256, 0, stream>>>(Wq, Wk, Wv, bq, bk, bv, Wcat, bcat);
  proj_kernel<<<dim3(64, 4, 10), 256, 0, stream>>>(x, Wcat, bcat, qarr, karr, vT);
  attn_kernel<<<512, 512, 0, stream>>>(qarr, karr, vT, x, gamma, out);
}